// Round 7
// baseline (198.838 us; speedup 1.0000x reference)
//
#include <hip/hip_runtime.h>
#include <hip/hip_bf16.h>

// Problem dims
#define B_   16
#define C_   256
#define HW_  3136      // 56*56
#define W_   56
#define CR_  128
#define KKG_ 144
#define G_   16
#define NPOS (B_*HW_)  // 50176
#define EPS_ 1e-5f
#define NBLK1 1568     // K1 grid: 16 b * 98 p-tiles of 32
#define NBLK3 784      // K3 grid: 16 b * 49 p-tiles of 64

typedef float f32x4 __attribute__((ext_vector_type(4)));
typedef short s16x8 __attribute__((ext_vector_type(8)));
typedef short s16x4 __attribute__((ext_vector_type(4)));

// ws layout (bytes):
//   t2   : [16 b][3136 p][128 o] bf16 (p-major)    = 12,845,056
//   kern : [16 b][144 row(g*9+kk)][3136 p] bf16    = 14,450,688
//   gacc : [256] f32 (sum[128]|sumsq[128])         = 1,024
//   wbfr : [128][256] bf16                         = 65,536
//   wbfs : [144][128] bf16                         = 36,864
#define T2_OFF_B    0
#define KERN_OFF_B  12845056
#define GACC_OFF_B  27295744
#define WBFR_OFF_B  27296768
#define WBFS_OFF_B  27362304

__device__ inline unsigned short f2bf(float f) {
    unsigned u = __float_as_uint(f);
    u += 0x7fff + ((u >> 16) & 1);          // RNE
    return (unsigned short)(u >> 16);
}
__device__ inline float bf2f(unsigned short h) {
    return __uint_as_float(((unsigned)h) << 16);
}
// packed f32 pair -> bf16 pair (v_cvt_pk_bf16_f32)
__device__ inline unsigned pkcvt(float a, float b) {
    float2 f2; f2.x = a; f2.y = b;
    __hip_bfloat162 h = __float22bfloat162_rn(f2);
    union { __hip_bfloat162 h2; unsigned u; } cv; cv.h2 = h;
    return cv.u;
}

// async global->LDS, 16B per lane: lane L lands at lds_base + L*16.
typedef const __attribute__((address_space(1))) unsigned int* gas_t;
typedef __attribute__((address_space(3))) unsigned int* las_t;
__device__ inline void gload_lds16(const void* g, void* l) {
    __builtin_amdgcn_global_load_lds((gas_t)g, (las_t)l, 16, 0, 0);
}
__device__ inline void barrier_raw() {
    __builtin_amdgcn_sched_barrier(0);
    __builtin_amdgcn_s_barrier();
    __builtin_amdgcn_sched_barrier(0);
}

// ---------------------------------------------------------------------------
// K0: cast weights to bf16 once + zero the BN accumulator.
// ---------------------------------------------------------------------------
__global__ __launch_bounds__(256) void prep_cast(
    const float* __restrict__ w_reduce, const float* __restrict__ w_span,
    unsigned short* __restrict__ wbfr, unsigned short* __restrict__ wbfs,
    float* __restrict__ gacc)
{
    int idx = blockIdx.x * 256 + threadIdx.x;
    if (idx < 256) gacc[idx] = 0.0f;
    if (idx < 32768) {
        wbfr[idx] = f2bf(w_reduce[idx]);
    } else {
        int k = idx - 32768;
        if (k < 18432) wbfs[k] = f2bf(w_span[k]);
    }
}

// ---------------------------------------------------------------------------
// K1: t2[b][p][o] = sum_c w_reduce[o][c] * x[b][c][p]   (bf16 MFMA 16x16x32)
// Counted-vmcnt 3-deep pipeline (T3/T4): stage chunk ch+2 via global_load_lds
// while computing chunk ch; raw s_barrier (no auto-drain) + inline-asm
// s_waitcnt vmcnt(3) so later chunks stay in flight across barriers.
// Block = 128 o x 32 p; 4 waves 2x2 over (64o x 16p). 1568 blocks.
// BN partials -> gacc[256] via f32 atomics (bn_finalize kernel deleted).
// t2 stored p-major for K3.
// ---------------------------------------------------------------------------
__global__ __launch_bounds__(256, 4) void reduce_mfma(
    const float* __restrict__ x, const unsigned short* __restrict__ wbfr,
    unsigned short* __restrict__ t2, float* __restrict__ gacc)
{
    __shared__ __align__(16) float xb3[3][1024];   // 3 x 4 KB  (B chunks)
    __shared__ __align__(16) short awb[3][4096];   // 3 x 8 KB  (A chunks)
    __shared__ float redp[128][2], redq[128][2];

    const int tid = threadIdx.x;
    const int lane = tid & 63, wv = tid >> 6;
    const int q = lane >> 4, i = lane & 15;
    const int q8 = q * 8;
    const int mrow = (wv & 1) * 64;          // o-half
    const int pw = (wv >> 1) * 16;           // p-half
    const int blk = blockIdx.x;
    const int b = blk / 98;
    const int p0 = (blk % 98) * 32;

    // ---- staging addresses (per thread) ----
    // B: unit U=tid -> c=U>>3, pu=U&7; source px-group pre-swizzled.
    const int c_st = tid >> 3;
    const int swz = ((tid & 7) ^ ((c_st >> 1) & 7)) * 4;
    const float* xlane = x + (size_t)b * C_ * HW_ + (size_t)c_st * HW_ + p0 + swz;
    // A: units U=tid (+256) -> o=U>>2, seg=U&3
    const unsigned short* wA0 = wbfr + (size_t)(tid >> 2) * C_ + (tid & 3) * 8;
    const unsigned short* wA1 = wA0 + (size_t)64 * C_;
    const int wvu4 = (tid & ~63) * 4;        // wave-uniform float idx
    const int wvu8 = (tid & ~63) * 8;        // wave-uniform short idx

    #define STAGE1(ch, bi) do {                                          \
        gload_lds16(xlane + (size_t)(ch) * 32 * HW_, &xb3[bi][wvu4]);    \
        gload_lds16(wA0 + (ch) * 32, &awb[bi][wvu8]);                    \
        gload_lds16(wA1 + (ch) * 32, &awb[bi][2048 + wvu8]);             \
    } while (0)

    // ---- frag-read constants ----
    const int p_loc = pw + i;
    const int pg = p_loc >> 2, pe = p_loc & 3;

    f32x4 acc[4] = {};

    // prologue: chunks 0,1 in flight (6 loads)
    STAGE1(0, 0);
    STAGE1(1, 1);

    #pragma unroll
    for (int ch = 0; ch < 8; ch++) {
        const int cur = ch % 3;
        if (ch < 7) asm volatile("s_waitcnt vmcnt(3)" ::: "memory");
        else        asm volatile("s_waitcnt vmcnt(0)" ::: "memory");
        barrier_raw();
        if (ch == 0) STAGE1(2, 2);
        if (ch == 1) STAGE1(3, 0);
        if (ch == 2) STAGE1(4, 1);
        if (ch == 3) STAGE1(5, 2);
        if (ch == 4) STAGE1(6, 0);
        if (ch == 5) STAGE1(7, 1);

        // A frags: rows stride 64B, 64 lanes tile 1024B -> conflict-free
        s16x8 af[4];
        #pragma unroll
        for (int mt = 0; mt < 4; mt++)
            af[mt] = *(const s16x8*)&awb[cur][(mrow + mt * 16 + i) * 32 + q8];
        // B frag: 8 f32 gathers (swizzled slots, ~2-way) + pack
        float f[8];
        #pragma unroll
        for (int k = 0; k < 8; k++) {
            int cl = q8 + k;
            int slot = pg ^ ((cl >> 1) & 7);
            f[k] = xb3[cur][cl * 32 + slot * 4 + pe];
        }
        union { s16x8 v; unsigned u[4]; } Bv;
        #pragma unroll
        for (int k2 = 0; k2 < 4; k2++) Bv.u[k2] = pkcvt(f[2*k2], f[2*k2+1]);

        #pragma unroll
        for (int mt = 0; mt < 4; mt++)
            acc[mt] = __builtin_amdgcn_mfma_f32_16x16x32_bf16(
                af[mt], Bv.v, acc[mt], 0, 0, 0);
    }
    #undef STAGE1

    // Epilogue: D col=i -> p, row=q*4+reg -> o. Store t2[b][p][o] (dwordx2).
    const int p = p0 + pw + i;
    #pragma unroll
    for (int mt = 0; mt < 4; mt++) {
        uint2 pr;
        pr.x = pkcvt(acc[mt][0], acc[mt][1]);
        pr.y = pkcvt(acc[mt][2], acc[mt][3]);
        *(uint2*)(t2 + ((size_t)b * HW_ + p) * CR_ + mrow + mt * 16 + q * 4) = pr;
        #pragma unroll
        for (int reg = 0; reg < 4; reg++) {
            float v = acc[mt][reg];
            float s = v, ss = v * v;
            #pragma unroll
            for (int m = 1; m < 16; m <<= 1) {
                s  += __shfl_xor(s, m);
                ss += __shfl_xor(ss, m);
            }
            if (i == 0) {
                int o = mrow + mt * 16 + q * 4 + reg;
                redp[o][wv >> 1] = s;
                redq[o][wv >> 1] = ss;
            }
        }
    }
    __syncthreads();
    if (tid < 128) atomicAdd(&gacc[tid], redp[tid][0] + redp[tid][1]);
    else           atomicAdd(&gacc[tid], redq[tid - 128][0] + redq[tid - 128][1]);
}

// ---------------------------------------------------------------------------
// K3: kern[b][g*9+kk][p] = sum_o w_span[kk*16+g][o]*relu(bn(t2[b][p][o])) + b
// Counted-vmcnt pipeline, 4 K-chunks. Full A (144x128 bf16, 36KB) staged ONCE
// in the preamble (row-XOR-swizzled); B (64p x 32c, 4KB) 3-deep -> vmcnt(1).
// BN scale/shift computed per block from gacc (128 rsqrt, free).
// Block: 144 o2 x 64 p; 4 waves split p 4-way. 784 blocks.
// ---------------------------------------------------------------------------
__global__ __launch_bounds__(256, 3) void span_mfma(
    const unsigned short* __restrict__ t2, const unsigned short* __restrict__ wbfs,
    const float* __restrict__ b_span, const float* __restrict__ gacc,
    const float* __restrict__ gamma, const float* __restrict__ beta,
    unsigned short* __restrict__ kern)
{
    __shared__ __align__(16) short aw[144 * 128];   // 36 KB, row-swizzled
    __shared__ __align__(16) short bb3[3][2048];    // 3 x 4 KB
    __shared__ float scs[128], shs[128], bsp[144];

    const int tid = threadIdx.x;
    const int lane = tid & 63, wv = tid >> 6;
    const int q = lane >> 4, i = lane & 15;
    const int q8 = q * 8;
    const int blk = blockIdx.x;
    const int b = blk / 49;
    const int p0 = (blk % 49) * 64;

    if (tid < 128) {
        float s = gacc[tid], ss = gacc[128 + tid];
        const float inv_n = 1.0f / (float)NPOS;
        float mu = s * inv_n;
        float var = ss * inv_n - mu * mu;
        float sc = gamma[tid] * rsqrtf(var + EPS_);
        scs[tid] = sc;
        shs[tid] = beta[tid] - mu * sc;
    }
    if (tid < 144) bsp[tid] = b_span[tid];
    __syncthreads();   // tables visible before the raw-barrier loop

    // B staging: unit U=tid -> p=U>>2, seg=U&3
    const unsigned short* tlane =
        t2 + ((size_t)b * HW_ + p0 + (tid >> 2)) * CR_ + (tid & 3) * 8;
    const int wvu8 = (tid & ~63) * 8;

    // prologue: A (9 insts, swizzled source) + B0 + B1  => 11 outstanding
    #pragma unroll
    for (int e = 0; e < 9; e++) {
        int U = tid + e * 256;                 // r = U>>4, u = U&15
        int r = U >> 4, u = U & 15;
        gload_lds16(wbfs + (size_t)r * CR_ + ((u ^ (r & 7)) * 8),
                    &aw[((tid & ~63) + e * 256) * 8]);
    }
    gload_lds16(tlane,      &bb3[0][wvu8]);
    gload_lds16(tlane + 32, &bb3[1][wvu8]);

    f32x4 acc[9] = {};

    #pragma unroll
    for (int ch = 0; ch < 4; ch++) {
        const int cur = ch % 3;
        if (ch < 3) asm volatile("s_waitcnt vmcnt(1)" ::: "memory");
        else        asm volatile("s_waitcnt vmcnt(0)" ::: "memory");
        barrier_raw();
        if (ch == 0) gload_lds16(tlane + 64, &bb3[2][wvu8]);
        if (ch == 1) gload_lds16(tlane + 96, &bb3[0][wvu8]);

        // B frag: one b128, rows stride 64B -> conflict-free
        s16x8 raw = *(const s16x8*)&bb3[cur][(wv * 16 + i) * 32 + q8];
        const int cb = ch * 32 + q8;
        float f[8];
        #pragma unroll
        for (int k = 0; k < 8; k++)
            f[k] = fmaxf(fmaf(bf2f((unsigned short)raw[k]),
                              scs[cb + k], shs[cb + k]), 0.0f);
        union { s16x8 v; unsigned u[4]; } Bv;
        #pragma unroll
        for (int k2 = 0; k2 < 4; k2++) Bv.u[k2] = pkcvt(f[2*k2], f[2*k2+1]);

        // A frags from swizzled LDS: u = ch*4 + q, slot = u ^ (r&7)
        #pragma unroll
        for (int mt = 0; mt < 9; mt++) {
            int r = mt * 16 + i;
            int slot = (ch * 4 + q) ^ (r & 7);
            s16x8 af = *(const s16x8*)&aw[r * 128 + slot * 8];
            acc[mt] = __builtin_amdgcn_mfma_f32_16x16x32_bf16(
                af, Bv.v, acc[mt], 0, 0, 0);
        }
    }

    // Epilogue: col=i -> p, row=q*4+reg -> o2 = kk*16+g; remap to g*9+kk
    const int p = p0 + wv * 16 + i;
    #pragma unroll
    for (int mt = 0; mt < 9; mt++) {
        #pragma unroll
        for (int reg = 0; reg < 4; reg++) {
            int o2 = mt * 16 + q * 4 + reg;
            int row = (o2 & 15) * 9 + (o2 >> 4);   // g*9 + kk
            kern[((size_t)b * KKG_ + row) * HW_ + p] = f2bf(acc[mt][reg] + bsp[o2]);
        }
    }
}

// ---------------------------------------------------------------------------
// K4: out[b, g*16+d, p] = sum_kk x[b, g*16+d, p+off(kk)] * kern[b][g*9+kk][p]
// 4 pixels/thread (one aligned quad, same row since 56%4==0). Per (d, di):
// one float4 + 2 edge-guarded scalars cover the 6-column window for all 3
// dj taps x 4 pixels -> 4x fewer memory instructions per pixel (the previous
// version was issue-bound: 169 scalar mem insts/px). float4 out stores.
// ---------------------------------------------------------------------------
__global__ __launch_bounds__(256) void involution_apply(
    const float* __restrict__ x, const unsigned short* __restrict__ kern,
    float* __restrict__ out)
{
    const int gtid = blockIdx.x * 256 + threadIdx.x;
    const int pu  = gtid % 784;          // pixel-quad index
    const int bg  = gtid / 784;
    const int g = bg & 15;
    const int b = bg >> 4;
    const int pix0 = pu * 4;
    const int h = pix0 / W_;
    const int w0 = pix0 % W_;

    // kernel values for the 4 pixels: kvf[kk][j]
    const unsigned short* kb = kern + ((size_t)(b * G_ + g) * 9) * HW_ + pix0;
    float kvf[9][4];
    #pragma unroll
    for (int kk = 0; kk < 9; kk++) {
        s16x4 kraw = *(const s16x4*)(kb + (size_t)kk * HW_);
        #pragma unroll
        for (int j = 0; j < 4; j++)
            kvf[kk][j] = bf2f((unsigned short)kraw[j]);
    }

    const float* xg = x + (size_t)(b * C_ + g * 16) * HW_;
    float* og = out + (size_t)(b * C_ + g * 16) * HW_ + pix0;

    const bool has_l = (w0 > 0);
    const bool has_r = (w0 + 4 < W_);
    const int loff = has_l ? (w0 - 1) : w0;        // clamped (no OOB addr)
    const int roff = has_r ? (w0 + 4) : w0;

    #pragma unroll
    for (int d = 0; d < 16; d++) {
        f32x4 acc = {0.0f, 0.0f, 0.0f, 0.0f};
        const float* xd = xg + (size_t)d * HW_;
        #pragma unroll
        for (int di = 0; di < 3; di++) {
            const int hh = h + di - 1;
            if (hh < 0 || hh >= W_) continue;
            const float* xr = xd + hh * W_;
            float4 mid = *(const float4*)(xr + w0);
            float lv = xr[loff];
            float rv = xr[roff];
            float win[6];
            win[0] = has_l ? lv : 0.0f;
            win[1] = mid.x; win[2] = mid.y; win[3] = mid.z; win[4] = mid.w;
            win[5] = has_r ? rv : 0.0f;
            #pragma unroll
            for (int dj = 0; dj < 3; dj++) {
                #pragma unroll
                for (int j = 0; j < 4; j++)
                    acc[j] = fmaf(win[dj + j], kvf[di * 3 + dj][j], acc[j]);
            }
        }
        *(f32x4*)(og + (size_t)d * HW_) = acc;
    }
}

extern "C" void kernel_launch(void* const* d_in, const int* in_sizes, int n_in,
                              void* d_out, int out_size, void* d_ws, size_t ws_size,
                              hipStream_t stream) {
    const float* x        = (const float*)d_in[0];
    const float* w_reduce = (const float*)d_in[1];
    // d_in[2] = b_reduce: unused — per-channel bias cancels exactly in BN.
    const float* gamma    = (const float*)d_in[3];
    const float* beta     = (const float*)d_in[4];
    const float* w_span   = (const float*)d_in[5];
    const float* b_span   = (const float*)d_in[6];
    float* out = (float*)d_out;

    char* wsb = (char*)d_ws;
    unsigned short* t2   = (unsigned short*)(wsb + T2_OFF_B);
    unsigned short* kern = (unsigned short*)(wsb + KERN_OFF_B);
    float*          gacc = (float*)(wsb + GACC_OFF_B);
    unsigned short* wbfr = (unsigned short*)(wsb + WBFR_OFF_B);
    unsigned short* wbfs = (unsigned short*)(wsb + WBFS_OFF_B);

    prep_cast<<<200, 256, 0, stream>>>(w_reduce, w_span, wbfr, wbfs, gacc);
    reduce_mfma<<<NBLK1, 256, 0, stream>>>(x, wbfr, t2, gacc);
    span_mfma<<<NBLK3, 256, 0, stream>>>(t2, wbfs, b_span, gacc, gamma, beta, kern);
    involution_apply<<<(B_ * G_ * HW_ / 4) / 256, 256, 0, stream>>>(x, kern, out);
}

// Round 8
// 170.013 us; speedup vs baseline: 1.1695x; 1.1695x over previous
//
#include <hip/hip_runtime.h>
#include <hip/hip_bf16.h>

// Problem dims
#define B_   16
#define C_   256
#define HW_  3136      // 56*56
#define W_   56
#define CR_  128
#define KKG_ 144
#define G_   16
#define NPOS (B_*HW_)  // 50176
#define EPS_ 1e-5f
#define NBLK 784       // 16 b * 49 p-tiles of 64  (K1 and K3)

typedef float f32x4 __attribute__((ext_vector_type(4)));
typedef short s16x8 __attribute__((ext_vector_type(8)));
typedef short s16x4 __attribute__((ext_vector_type(4)));

// ws layout (bytes):
//   t2   : [16 b][3136 p][128 o] bf16 (p-major)    = 12,845,056
//   kern : [16 b][144 row(g*9+kk)][3136 p] bf16    = 14,450,688
//   gp   : [256 ch][784 blk] f32                   = 802,816
//   stats: scale[128]|shift[128] f32               = 1,024
//   wbfr : [128][256] bf16                         = 65,536
//   wbfs : [144][128] bf16                         = 36,864
#define T2_OFF_B    0
#define KERN_OFF_B  12845056
#define GP_OFF_B    27295744
#define STAT_OFF_B  28098560
#define WBFR_OFF_B  28099584
#define WBFS_OFF_B  28165120

__device__ inline unsigned short f2bf(float f) {
    unsigned u = __float_as_uint(f);
    u += 0x7fff + ((u >> 16) & 1);          // RNE
    return (unsigned short)(u >> 16);
}
__device__ inline float bf2f(unsigned short h) {
    return __uint_as_float(((unsigned)h) << 16);
}
// packed f32 pair -> bf16 pair (v_cvt_pk_bf16_f32)
__device__ inline unsigned pkcvt(float a, float b) {
    float2 f2; f2.x = a; f2.y = b;
    __hip_bfloat162 h = __float22bfloat162_rn(f2);
    union { __hip_bfloat162 h2; unsigned u; } cv; cv.h2 = h;
    return cv.u;
}

// async global->LDS, 16B per lane: lane L lands at lds_base + L*16.
typedef const __attribute__((address_space(1))) unsigned int* gas_t;
typedef __attribute__((address_space(3))) unsigned int* las_t;
__device__ inline void gload_lds16(const void* g, void* l) {
    __builtin_amdgcn_global_load_lds((gas_t)g, (las_t)l, 16, 0, 0);
}
__device__ inline void barrier_raw() {
    __builtin_amdgcn_sched_barrier(0);
    __builtin_amdgcn_s_barrier();
    __builtin_amdgcn_sched_barrier(0);
}

// ---------------------------------------------------------------------------
// K0: cast weights to bf16 once.
// ---------------------------------------------------------------------------
__global__ __launch_bounds__(256) void prep_cast(
    const float* __restrict__ w_reduce, const float* __restrict__ w_span,
    unsigned short* __restrict__ wbfr, unsigned short* __restrict__ wbfs)
{
    int idx = blockIdx.x * 256 + threadIdx.x;
    if (idx < 32768) {
        wbfr[idx] = f2bf(w_reduce[idx]);
    } else {
        int k = idx - 32768;
        if (k < 18432) wbfs[k] = f2bf(w_span[k]);
    }
}

// ---------------------------------------------------------------------------
// K1: t2[b][p][o] = sum_c w_reduce[o][c] * x[b][c][p]   (bf16 MFMA 16x16x32)
// m97-proportioned retile: block = 128 o x 64 p, 4 waves 2x2 over (64o x 32p)
// -> 8 MFMA per chunk per wave (2x the old 32p tile) so compute covers the
// staged-load latency between barriers. Counted-vmcnt 3-deep pipeline:
// stage chunk ch+2 (4 x gload_lds16/thread: A 8KB + B 8KB) while computing
// chunk ch; raw s_barrier + s_waitcnt vmcnt(4) keeps later chunks in flight.
// B LDS layout [32 c][16 groups of 4 px] f32 with group-XOR swizzle
// (slot = pu ^ ((c>>2)&7), pre-applied on the GLOBAL source) so the frag
// gathers spread q-groups across bank octets (<=2-way = free).
// Grid 784 = 3.06 blocks/CU; LDS 50KB -> 3 blocks/CU (exact fit).
// BN partials -> gp[ch][blk] stores (NO atomics — R7's 1568-way-contended
// atomicAdd tail cost ~22us). t2 stored p-major for K3.
// ---------------------------------------------------------------------------
__global__ __launch_bounds__(256, 3) void reduce_mfma(
    const float* __restrict__ x, const unsigned short* __restrict__ wbfr,
    unsigned short* __restrict__ t2, float* __restrict__ gp)
{
    __shared__ __align__(16) float xb3[3][2048];   // 3 x 8 KB  (B chunks)
    __shared__ __align__(16) short awb[3][4096];   // 3 x 8 KB  (A chunks)
    __shared__ float redp[128][2], redq[128][2];

    const int tid = threadIdx.x;
    const int lane = tid & 63, wv = tid >> 6;
    const int q = lane >> 4, i = lane & 15;
    const int q8 = q * 8;
    const int mrow = (wv & 1) * 64;          // o-half
    const int pw = (wv >> 1) * 32;           // p-half
    const int blk = blockIdx.x;
    const int b = blk / 49;
    const int p0 = (blk % 49) * 64;

    // ---- staging addresses (per thread) ----
    // B: 2 issues. Issue e covers channels ce=tid>>4 (+16e), slot=tid&15;
    // LDS [c][slot] holds pixel-group (slot ^ ((c>>2)&7)) — swizzle applied
    // on the global source, LDS dest linear.
    const int ce0 = tid >> 4, slot = tid & 15;
    const int ce1 = ce0 + 16;
    const float* xs0 = x + (size_t)b * C_ * HW_ + (size_t)ce0 * HW_ + p0
                         + ((slot ^ ((ce0 >> 2) & 7)) << 2);
    const float* xs1 = x + (size_t)b * C_ * HW_ + (size_t)ce1 * HW_ + p0
                         + ((slot ^ ((ce1 >> 2) & 7)) << 2);
    // A: 2 issues: rows tid>>2 and +64, seg tid&3 (16B each)
    const unsigned short* wA0 = wbfr + (size_t)(tid >> 2) * C_ + (tid & 3) * 8;
    const unsigned short* wA1 = wA0 + (size_t)64 * C_;
    const int wvu4 = (tid & ~63) * 4;        // wave-uniform float idx
    const int wvu8 = (tid & ~63) * 8;        // wave-uniform short idx

    #define STAGE1(ch, bi) do {                                            \
        gload_lds16(xs0 + (size_t)(ch) * 32 * HW_, &xb3[bi][wvu4]);        \
        gload_lds16(xs1 + (size_t)(ch) * 32 * HW_, &xb3[bi][1024 + wvu4]); \
        gload_lds16(wA0 + (ch) * 32, &awb[bi][wvu8]);                      \
        gload_lds16(wA1 + (ch) * 32, &awb[bi][2048 + wvu8]);               \
    } while (0)

    f32x4 acc[4][2] = {};

    // prologue: chunks 0,1 in flight (8 loads)
    STAGE1(0, 0);
    STAGE1(1, 1);

    #pragma unroll
    for (int ch = 0; ch < 8; ch++) {
        const int cur = ch % 3;
        if (ch < 7) asm volatile("s_waitcnt vmcnt(4)" ::: "memory");
        else        asm volatile("s_waitcnt vmcnt(0)" ::: "memory");
        barrier_raw();
        if (ch == 0) STAGE1(2, 2);
        if (ch == 1) STAGE1(3, 0);
        if (ch == 2) STAGE1(4, 1);
        if (ch == 3) STAGE1(5, 2);
        if (ch == 4) STAGE1(6, 0);
        if (ch == 5) STAGE1(7, 1);

        // A frags: row*32 shorts, contiguous rows 0..127
        s16x8 af[4];
        #pragma unroll
        for (int mt = 0; mt < 4; mt++)
            af[mt] = *(const s16x8*)&awb[cur][(mrow + mt * 16 + i) * 32 + q8];

        // B frags: 8 f32 gathers per nt (swizzled slots, <=2-way) + pack
        s16x8 bfr[2];
        #pragma unroll
        for (int nt = 0; nt < 2; nt++) {
            const int p_loc = pw + nt * 16 + i;
            const int pg = p_loc >> 2, pe = p_loc & 3;
            float f[8];
            #pragma unroll
            for (int k = 0; k < 8; k++) {
                int cl = q8 + k;
                f[k] = xb3[cur][cl * 64 + ((pg ^ ((cl >> 2) & 7)) << 2) + pe];
            }
            union { s16x8 v; unsigned u[4]; } Bv;
            #pragma unroll
            for (int k2 = 0; k2 < 4; k2++) Bv.u[k2] = pkcvt(f[2*k2], f[2*k2+1]);
            bfr[nt] = Bv.v;
        }

        #pragma unroll
        for (int mt = 0; mt < 4; mt++)
            #pragma unroll
            for (int nt = 0; nt < 2; nt++)
                acc[mt][nt] = __builtin_amdgcn_mfma_f32_16x16x32_bf16(
                    af[mt], bfr[nt], acc[mt][nt], 0, 0, 0);
    }
    #undef STAGE1

    // Epilogue: D col=i -> p, row=q*4+reg -> o. Store t2[b][p][o] (dwordx2).
    #pragma unroll
    for (int mt = 0; mt < 4; mt++) {
        #pragma unroll
        for (int nt = 0; nt < 2; nt++) {
            int p = p0 + pw + nt * 16 + i;
            uint2 pr;
            pr.x = pkcvt(acc[mt][nt][0], acc[mt][nt][1]);
            pr.y = pkcvt(acc[mt][nt][2], acc[mt][nt][3]);
            *(uint2*)(t2 + ((size_t)b * HW_ + p) * CR_ + mrow + mt * 16 + q * 4) = pr;
        }
        // BN partials: sum over nt and the 16 i-lanes
        #pragma unroll
        for (int reg = 0; reg < 4; reg++) {
            float v0 = acc[mt][0][reg], v1 = acc[mt][1][reg];
            float s = v0 + v1;
            float ss = v0 * v0 + v1 * v1;
            #pragma unroll
            for (int m = 1; m < 16; m <<= 1) {
                s  += __shfl_xor(s, m);
                ss += __shfl_xor(ss, m);
            }
            if (i == 0) {
                int o = mrow + mt * 16 + q * 4 + reg;
                redp[o][wv >> 1] = s;
                redq[o][wv >> 1] = ss;
            }
        }
    }
    __syncthreads();
    if (tid < 128)
        gp[(size_t)tid * NBLK + blk] = redp[tid][0] + redp[tid][1];
    else
        gp[(size_t)tid * NBLK + blk] = redq[tid - 128][0] + redq[tid - 128][1];
}

// ---------------------------------------------------------------------------
// K2: sum partials -> scale/shift. One block per channel, coalesced reads.
// ---------------------------------------------------------------------------
__global__ __launch_bounds__(256) void bn_finalize(
    const float* __restrict__ gp, const float* __restrict__ gamma,
    const float* __restrict__ beta, float* __restrict__ stats)
{
    const int o = blockIdx.x;
    const int tid = threadIdx.x;
    float s = 0.f, ss = 0.f;
    for (int idx = tid; idx < NBLK; idx += 256) {
        s  += gp[(size_t)o * NBLK + idx];
        ss += gp[(size_t)(128 + o) * NBLK + idx];
    }
    #pragma unroll
    for (int m = 1; m < 64; m <<= 1) {
        s  += __shfl_xor(s, m);
        ss += __shfl_xor(ss, m);
    }
    __shared__ float rs[4], rss[4];
    if ((tid & 63) == 0) { rs[tid >> 6] = s; rss[tid >> 6] = ss; }
    __syncthreads();
    if (tid == 0) {
        s  = rs[0] + rs[1] + rs[2] + rs[3];
        ss = rss[0] + rss[1] + rss[2] + rss[3];
        float inv_n = 1.0f / (float)NPOS;
        float mu = s * inv_n;
        float var = ss * inv_n - mu * mu;
        float sc = gamma[o] * rsqrtf(var + EPS_);
        stats[o] = sc;
        stats[128 + o] = beta[o] - mu * sc;
    }
}

// ---------------------------------------------------------------------------
// K3: kern[b][g*9+kk][p] = sum_o w_span[kk*16+g][o]*relu(bn(t2[b][p][o])) + b
// Counted-vmcnt pipeline, 4 K-chunks. Full A (144x128 bf16, 36KB) staged ONCE
// in the preamble (row-XOR-swizzled); B (64p x 32c, 4KB) 3-deep -> vmcnt(1).
// Block: 144 o2 x 64 p; 4 waves split p 4-way. 784 blocks.
// ---------------------------------------------------------------------------
__global__ __launch_bounds__(256, 3) void span_mfma(
    const unsigned short* __restrict__ t2, const unsigned short* __restrict__ wbfs,
    const float* __restrict__ b_span, const float* __restrict__ stats,
    unsigned short* __restrict__ kern)
{
    __shared__ __align__(16) short aw[144 * 128];   // 36 KB, row-swizzled
    __shared__ __align__(16) short bb3[3][2048];    // 3 x 4 KB
    __shared__ float scs[128], shs[128], bsp[144];

    const int tid = threadIdx.x;
    const int lane = tid & 63, wv = tid >> 6;
    const int q = lane >> 4, i = lane & 15;
    const int q8 = q * 8;
    const int blk = blockIdx.x;
    const int b = blk / 49;
    const int p0 = (blk % 49) * 64;

    if (tid < 128) { scs[tid] = stats[tid]; shs[tid] = stats[128 + tid]; }
    if (tid < 144) bsp[tid] = b_span[tid];
    __syncthreads();   // tables visible before the raw-barrier loop

    // B staging: unit U=tid -> p=U>>2, seg=U&3
    const unsigned short* tlane =
        t2 + ((size_t)b * HW_ + p0 + (tid >> 2)) * CR_ + (tid & 3) * 8;
    const int wvu8 = (tid & ~63) * 8;

    // prologue: A (9 insts, swizzled source) + B0 + B1  => 11 outstanding
    #pragma unroll
    for (int e = 0; e < 9; e++) {
        int U = tid + e * 256;                 // r = U>>4, u = U&15
        int r = U >> 4, u = U & 15;
        gload_lds16(wbfs + (size_t)r * CR_ + ((u ^ (r & 7)) * 8),
                    &aw[((tid & ~63) + e * 256) * 8]);
    }
    gload_lds16(tlane,      &bb3[0][wvu8]);
    gload_lds16(tlane + 32, &bb3[1][wvu8]);

    f32x4 acc[9] = {};

    #pragma unroll
    for (int ch = 0; ch < 4; ch++) {
        const int cur = ch % 3;
        if (ch < 3) asm volatile("s_waitcnt vmcnt(1)" ::: "memory");
        else        asm volatile("s_waitcnt vmcnt(0)" ::: "memory");
        barrier_raw();
        if (ch == 0) gload_lds16(tlane + 64, &bb3[2][wvu8]);
        if (ch == 1) gload_lds16(tlane + 96, &bb3[0][wvu8]);

        // B frag: one b128, rows stride 64B -> conflict-free
        s16x8 raw = *(const s16x8*)&bb3[cur][(wv * 16 + i) * 32 + q8];
        const int cb = ch * 32 + q8;
        float f[8];
        #pragma unroll
        for (int k = 0; k < 8; k++)
            f[k] = fmaxf(fmaf(bf2f((unsigned short)raw[k]),
                              scs[cb + k], shs[cb + k]), 0.0f);
        union { s16x8 v; unsigned u[4]; } Bv;
        #pragma unroll
        for (int k2 = 0; k2 < 4; k2++) Bv.u[k2] = pkcvt(f[2*k2], f[2*k2+1]);

        // A frags from swizzled LDS: u = ch*4 + q, slot = u ^ (r&7)
        #pragma unroll
        for (int mt = 0; mt < 9; mt++) {
            int r = mt * 16 + i;
            int slot = (ch * 4 + q) ^ (r & 7);
            s16x8 af = *(const s16x8*)&aw[r * 128 + slot * 8];
            acc[mt] = __builtin_amdgcn_mfma_f32_16x16x32_bf16(
                af, Bv.v, acc[mt], 0, 0, 0);
        }
    }

    // Epilogue: col=i -> p, row=q*4+reg -> o2 = kk*16+g; remap to g*9+kk
    const int p = p0 + wv * 16 + i;
    #pragma unroll
    for (int mt = 0; mt < 9; mt++) {
        #pragma unroll
        for (int reg = 0; reg < 4; reg++) {
            int o2 = mt * 16 + q * 4 + reg;
            int row = (o2 & 15) * 9 + (o2 >> 4);   // g*9 + kk
            kern[((size_t)b * KKG_ + row) * HW_ + p] = f2bf(acc[mt][reg] + bsp[o2]);
        }
    }
}

// ---------------------------------------------------------------------------
// K4: out[b, g*16+d, p] = sum_kk x[b, g*16+d, p+off(kk)] * kern[b][g*9+kk][p]
// 4 pixels/thread (aligned quad, never crosses a row since 56%4==0).
// Per (d, di): one float4 + 2 edge-guarded scalars cover the 6-column window
// for all 3 dj taps x 4 pixels -> ~42 mem insts/pixel vs 169 scalar before.
// ---------------------------------------------------------------------------
__global__ __launch_bounds__(256) void involution_apply(
    const float* __restrict__ x, const unsigned short* __restrict__ kern,
    float* __restrict__ out)
{
    const int gtid = blockIdx.x * 256 + threadIdx.x;
    const int pu  = gtid % 784;          // pixel-quad index
    const int bg  = gtid / 784;
    const int g = bg & 15;
    const int b = bg >> 4;
    const int pix0 = pu * 4;
    const int h = pix0 / W_;
    const int w0 = pix0 % W_;

    // kernel values for the 4 pixels: kvf[kk][j]
    const unsigned short* kb = kern + ((size_t)(b * G_ + g) * 9) * HW_ + pix0;
    float kvf[9][4];
    #pragma unroll
    for (int kk = 0; kk < 9; kk++) {
        s16x4 kraw = *(const s16x4*)(kb + (size_t)kk * HW_);
        #pragma unroll
        for (int j = 0; j < 4; j++)
            kvf[kk][j] = bf2f((unsigned short)kraw[j]);
    }

    const float* xg = x + (size_t)(b * C_ + g * 16) * HW_;
    float* og = out + (size_t)(b * C_ + g * 16) * HW_ + pix0;

    const bool has_l = (w0 > 0);
    const bool has_r = (w0 + 4 < W_);
    const int loff = has_l ? (w0 - 1) : w0;        // clamped (no OOB addr)
    const int roff = has_r ? (w0 + 4) : w0;

    #pragma unroll
    for (int d = 0; d < 16; d++) {
        f32x4 acc = {0.0f, 0.0f, 0.0f, 0.0f};
        const float* xd = xg + (size_t)d * HW_;
        #pragma unroll
        for (int di = 0; di < 3; di++) {
            const int hh = h + di - 1;
            if (hh < 0 || hh >= W_) continue;
            const float* xr = xd + hh * W_;
            float4 mid = *(const float4*)(xr + w0);
            float lv = xr[loff];
            float rv = xr[roff];
            float win[6];
            win[0] = has_l ? lv : 0.0f;
            win[1] = mid.x; win[2] = mid.y; win[3] = mid.z; win[4] = mid.w;
            win[5] = has_r ? rv : 0.0f;
            #pragma unroll
            for (int dj = 0; dj < 3; dj++) {
                #pragma unroll
                for (int j = 0; j < 4; j++)
                    acc[j] = fmaf(win[dj + j], kvf[di * 3 + dj][j], acc[j]);
            }
        }
        *(f32x4*)(og + (size_t)d * HW_) = acc;
    }
}

extern "C" void kernel_launch(void* const* d_in, const int* in_sizes, int n_in,
                              void* d_out, int out_size, void* d_ws, size_t ws_size,
                              hipStream_t stream) {
    const float* x        = (const float*)d_in[0];
    const float* w_reduce = (const float*)d_in[1];
    // d_in[2] = b_reduce: unused — per-channel bias cancels exactly in BN.
    const float* gamma    = (const float*)d_in[3];
    const float* beta     = (const float*)d_in[4];
    const float* w_span   = (const float*)d_in[5];
    const float* b_span   = (const float*)d_in[6];
    float* out = (float*)d_out;

    char* wsb = (char*)d_ws;
    unsigned short* t2   = (unsigned short*)(wsb + T2_OFF_B);
    unsigned short* kern = (unsigned short*)(wsb + KERN_OFF_B);
    float*          gp    = (float*)(wsb + GP_OFF_B);
    float*          stats = (float*)(wsb + STAT_OFF_B);
    unsigned short* wbfr = (unsigned short*)(wsb + WBFR_OFF_B);
    unsigned short* wbfs = (unsigned short*)(wsb + WBFS_OFF_B);

    prep_cast<<<200, 256, 0, stream>>>(w_reduce, w_span, wbfr, wbfs);
    reduce_mfma<<<NBLK, 256, 0, stream>>>(x, wbfr, t2, gp);
    bn_finalize<<<128, 256, 0, stream>>>(gp, gamma, beta, stats);
    span_mfma<<<NBLK, 256, 0, stream>>>(t2, wbfs, b_span, stats, kern);
    involution_apply<<<(B_ * G_ * HW_ / 4) / 256, 256, 0, stream>>>(x, kern, out);
}